// Round 11
// baseline (181.609 us; speedup 1.0000x reference)
//
#include <hip/hip_runtime.h>
#include <math.h>

#define B_ 32
#define C_ 64
#define L_ 16384
#define LT 64                           // l-columns per tile
#define NT 8                            // tiles per block (window = 512 l)
#define NBLK (B_ * (L_ / (LT * NT)))    // 1024 blocks -> exactly 4/CU resident

typedef __attribute__((ext_vector_type(8))) short short8;
typedef __attribute__((ext_vector_type(4))) float f32x4;

__device__ __forceinline__ unsigned short f2bf(float x) {
  unsigned int u = __builtin_bit_cast(unsigned int, x);
  u += 0x7fffu + ((u >> 16) & 1u);   // RNE
  return (unsigned short)(u >> 16);
}

__device__ __forceinline__ float lrelu(float x) {
  return x >= 0.f ? x : 0.1f * x;
}

__device__ __forceinline__ void load_lds_16(const void* g, void* l) {
  __builtin_amdgcn_global_load_lds(
      (const __attribute__((address_space(1))) void*)g,
      (__attribute__((address_space(3))) void*)l, 16, 0, 0);
}
__device__ __forceinline__ void load_lds_4(const void* g, void* l) {
  __builtin_amdgcn_global_load_lds(
      (const __attribute__((address_space(1))) void*)g,
      (__attribute__((address_space(3))) void*)l, 4, 0, 0);
}

// ---------------------------------------------------------------------------
// Prep (tiny): kern4[b,c,4], att[b,c], wfrag = conv_w as bf16 A-frags in
// per-lane load order (unchanged from r4-r10).
// ---------------------------------------------------------------------------
__global__ void da_prep(const float* __restrict__ x1,
                        const float* __restrict__ W1,
                        const float* __restrict__ W2,
                        const float* __restrict__ ca_w1,
                        const float* __restrict__ ca_w2,
                        const float* __restrict__ conv_w,
                        float* __restrict__ kern4,
                        float* __restrict__ att,
                        unsigned short* __restrict__ wfrag) {
  int b = blockIdx.x;      // 32
  int t = threadIdx.x;     // 64
  __shared__ float x1s[64], h[64], a1[8];
  x1s[t] = x1[b * 64 + t];
  __syncthreads();
  {
    const float* w1r = W1 + t * 64;
    float s = 0.f;
    #pragma unroll
    for (int i = 0; i < 64; ++i) s = fmaf(x1s[i], w1r[i], s);
    h[t] = lrelu(s);
  }
  if (t < 8) {
    const float* cw = ca_w1 + t * 64;
    float a = 0.f;
    #pragma unroll
    for (int i = 0; i < 64; ++i) a = fmaf(x1s[i], cw[i], a);
    a1[t] = lrelu(a);
  }
  __syncthreads();
  #pragma unroll
  for (int kk = 0; kk < 3; ++kk) {
    const float* w2r = W2 + (t * 3 + kk) * 64;
    float s2 = 0.f;
    #pragma unroll
    for (int i = 0; i < 64; ++i) s2 = fmaf(h[i], w2r[i], s2);
    kern4[(b * 64 + t) * 4 + kk] = s2;
  }
  kern4[(b * 64 + t) * 4 + 3] = 0.f;
  {
    float a = 0.f;
    #pragma unroll
    for (int r = 0; r < 8; ++r) a = fmaf(a1[r], ca_w2[t * 8 + r], a);
    att[b * 64 + t] = 1.f / (1.f + expf(-a));
  }
  if (b == 0) {
    #pragma unroll
    for (int kt = 0; kt < 2; ++kt)
      #pragma unroll
      for (int mt = 0; mt < 4; ++mt)
        #pragma unroll
        for (int j = 0; j < 8; ++j) {
          float e = conv_w[(mt * 16 + (t & 15)) * 64 + kt * 32 + (t >> 4) * 8 + j];
          wfrag[(((kt * 4 + mt) * 64) + t) * 8 + j] = f2bf(e);
        }
  }
}

// ---------------------------------------------------------------------------
// Main: LT=64, NBUF=2, midT ALIASED into buf[cur] (r9-proven), 33 KB LDS ->
// exactly 4 blocks/CU, grid 1024 all-resident.  2 barriers per 32 KB moved
// (r8 paid 2 per 16 KB).  Per-wave in-loop vmem = 4 stage glds (+1 halo
// glds on wave3) + 16 stores -> uniform vmcnt(16) retires stage(t)(+halo),
// keeps stores(t-1) in flight; never drains stores mid-loop.
//
// Iter t:  [vmcnt(16)] [barrier_A: every wave's stage(t) retired -> tile t
// published] [step1: ALL buf[cur] reads -> regs: q(4xb128), prev/nxt, xv,
// haloL handoff] [lgkm0 + barrier_B] [STAGE(t+1)->buf[cur^1]; wave3
// HALO(t+1)->haloR strip] [PhaseA -> midT aliased in buf[cur] rows 0-31]
// [PhaseB MFMA (wave-private midT rows l in [16w,16w+16))] [16 stores].
//
// Race audit: (1) reader vs issuer glds: issuer's vmcnt(16) precedes ITS
// barrier_A(t); readers touch tile t after barrier_A(t). (2) midT alias:
// all buf[cur] reads are pre-barrier_B; midT writes post-barrier_B.
// (3) STAGE(t+1) overwrites tile t-1 + midT(t-1): their last readers
// (PhaseB(t-1)) precede barrier_A(t) in program order. (4) haloL: wave3
// ds_write in step1(t), drained by lgkm0 before barrier_B(t); wave0 reads
// in step1(t+1) after barrier_A(t+1). (5) haloR is wave3-private (own glds,
// own vmcnt, own read). prev for wave0 comes from haloL strip because
// midT(t-1) clobbered rows c<32 of the old buffer.
// ---------------------------------------------------------------------------
__global__ __launch_bounds__(256, 4) void da_main(
    const float* __restrict__ x0,
    const float* __restrict__ conv_b,
    const float* __restrict__ kern4,
    const float* __restrict__ att,
    const unsigned short* __restrict__ wfrag,
    float* __restrict__ out) {
  __shared__ float x0s[2][64 * LT];      // 2 x 16 KB (midT aliases cur 8 KB)
  __shared__ float haloR[2][64];         // right-halo strips (wave3 glds)
  __shared__ float haloL[2][64];         // left-halo handoff (wave3->wave0)

  int bid = blockIdx.x;            // 0..1023
  int b = bid >> 5;                // 32 windows per batch
  int base_l = (bid & 31) * (NT * LT);   // 512-l window
  int tid = threadIdx.x;
  int lane = tid & 63;
  int wave = tid >> 6;

  int m_lane = lane & 15;
  int qq = lane >> 4;
  int kbase = qq * 8;
  int wl = wave * 16 + m_lane;     // this thread's l (Phase B / epilogue)
  int cs = lane & 7;
  bool lastw = (base_l + NT * LT) >= L_;

  const float* xb = x0 + (size_t)(b * 64) * L_;

  // ---- async stage of tile t1 into buffer dd (4 glds/wave, 4 rows each)
  auto STAGE = [&](int t1, int dd) {
    #pragma unroll
    for (int i = 0; i < 4; ++i) {
      int rg = wave * 16 + i * 4;          // row-group of 4 rows (1 KB)
      int c = rg + (lane >> 4);
      int p = (lane & 15) ^ (c & 7);       // global chunk for LDS slot lane&15
      const float* gp = xb + (size_t)c * L_ + base_l + t1 * LT + (p << 2);
      load_lds_16(gp, &x0s[dd][rg * LT]);
    }
  };
  // ---- right-halo strip for tile t1: element l = base_l + (t1+1)*LT, all c
  auto HALO = [&](int t1) {                // call from wave 3 only
    int l = base_l + (t1 + 1) * LT;
    if (l >= L_) l = 0;                    // clamp; PhaseA substitutes 0
    load_lds_4(xb + (size_t)lane * L_ + l, &haloR[t1 & 1][0]);
  };

  // ---- pre-loop register loads
  short8 af[2][4];
  #pragma unroll
  for (int kt = 0; kt < 2; ++kt)
    #pragma unroll
    for (int mt = 0; mt < 4; ++mt)
      af[kt][mt] = *(const short8*)&wfrag[(((kt * 4 + mt) * 64) + lane) * 8];

  float4 kv = *(const float4*)&kern4[(b * 64 + lane) * 4];
  float k0 = kv.x, k1 = kv.y, k2 = kv.z;

  float cb_r[4][4], at_r[4][4];
  #pragma unroll
  for (int mt = 0; mt < 4; ++mt)
    #pragma unroll
    for (int r = 0; r < 4; ++r) {
      int o = mt * 16 + qq * 4 + r;
      cb_r[mt][r] = conv_b[o];
      at_r[mt][r] = att[b * 64 + o];
    }

  float hl0 = 0.f;                 // window-left edge halo
  if (wave == 0 && base_l > 0) hl0 = xb[(size_t)lane * L_ + base_l - 1];

  __syncthreads();                 // drains vmcnt(0)+lgkmcnt(0) of all above

  // ---- prologue: stage tile 0 (+ its right-halo strip)
  STAGE(0, 0);
  if (wave == 3) HALO(0);

  int cur = 0;
  for (int t = 0; t < NT; ++t) {
    // counted wait: stage(t)(+halo) retired; stores(t-1) stay in flight
    if (t == 0)
      asm volatile("s_waitcnt vmcnt(0)" ::: "memory");
    else
      asm volatile("s_waitcnt vmcnt(16)" ::: "memory");
    __builtin_amdgcn_s_barrier();   // barrier_A: tile t published (all waves)

    // ---- step1: ALL reads of buf[cur] (and halo strips) into registers
    const float* row = &x0s[cur][lane * LT];
    float4 q[4];
    #pragma unroll
    for (int i = 0; i < 4; ++i)
      q[i] = *(const float4*)&row[((4 * wave + i) ^ cs) << 2];

    float prev;
    if (wave == 0) prev = (t == 0) ? hl0 : haloL[t & 1][lane];
    else           prev = row[(((4 * wave - 1) ^ cs) << 2) + 3];
    float nxtv;
    if (wave == 3) nxtv = (lastw && t == NT - 1) ? 0.f : haloR[t & 1][lane];
    else           nxtv = row[((4 * wave + 4) ^ cs) << 2];
    if (wave == 3) haloL[(t + 1) & 1][lane] = q[3].w;   // handoff for t+1

    float xv[4][4];                 // residual x0 for epilogue
    #pragma unroll
    for (int mt = 0; mt < 4; ++mt)
      #pragma unroll
      for (int r = 0; r < 4; ++r) {
        int o = mt * 16 + qq * 4 + r;
        xv[mt][r] =
            x0s[cur][o * LT + (((wl >> 2) ^ (o & 7)) << 2) + (wl & 3)];
      }

    asm volatile("s_waitcnt lgkmcnt(0)" ::: "memory");
    __builtin_amdgcn_s_barrier();   // barrier_B: reads done, writes may begin
    asm volatile("" ::: "memory");

    // ---- stage tile t+1 (buf[cur^1] free: its readers passed barrier_A)
    if (t + 1 < NT) {
      STAGE(t + 1, cur ^ 1);
      if (wave == 3) HALO(t + 1);
    }

    // ---- Phase A: depthwise 3-tap + lrelu -> midT (aliased, rows c<32)
    {
      unsigned short* mid = (unsigned short*)&x0s[cur][0];
      float xa[16] = {q[0].x, q[0].y, q[0].z, q[0].w, q[1].x, q[1].y,
                      q[1].z, q[1].w, q[2].x, q[2].y, q[2].z, q[2].w,
                      q[3].x, q[3].y, q[3].z, q[3].w};
      int lb = wave * 16;
      #pragma unroll
      for (int j = 0; j < 16; ++j) {
        float xm = (j == 0) ? prev : xa[j - 1];
        float xp = (j == 15) ? nxtv : xa[j + 1];
        float m = fmaf(k0, xm, fmaf(k1, xa[j], k2 * xp));
        mid[(lb + j) * 64 + (lane ^ ((j & 7) << 3))] = f2bf(lrelu(m));
      }
    }

    // ---- Phase B: wave-private midT rows -> 16x16x32 bf16 MFMA
    f32x4 acc[4];
    #pragma unroll
    for (int mt = 0; mt < 4; ++mt) acc[mt] = (f32x4){0.f, 0.f, 0.f, 0.f};
    {
      const unsigned short* mid = (const unsigned short*)&x0s[cur][0];
      #pragma unroll
      for (int kt = 0; kt < 2; ++kt) {
        int cb = kt * 32 + kbase;
        const short8 bf =
            *(const short8*)&mid[wl * 64 + (cb ^ ((wl & 7) << 3))];
        #pragma unroll
        for (int mt = 0; mt < 4; ++mt)
          acc[mt] = __builtin_amdgcn_mfma_f32_16x16x32_bf16(af[kt][mt], bf,
                                                            acc[mt], 0, 0, 0);
      }
    }

    // ---- epilogue + 16 stores (never waited on mid-loop)
    {
      size_t obase = (size_t)(b * 64) * L_ + base_l + t * LT + wl;
      #pragma unroll
      for (int mt = 0; mt < 4; ++mt)
        #pragma unroll
        for (int r = 0; r < 4; ++r) {
          int o = mt * 16 + qq * 4 + r;
          out[obase + (size_t)o * L_] =
              acc[mt][r] + cb_r[mt][r] + xv[mt][r] * at_r[mt][r];
        }
    }

    cur ^= 1;
  }
}

extern "C" void kernel_launch(void* const* d_in, const int* in_sizes, int n_in,
                              void* d_out, int out_size, void* d_ws, size_t ws_size,
                              hipStream_t stream) {
  const float* x0     = (const float*)d_in[0];
  const float* x1     = (const float*)d_in[1];
  const float* W1     = (const float*)d_in[2];
  const float* W2     = (const float*)d_in[3];
  const float* conv_w = (const float*)d_in[4];
  const float* conv_b = (const float*)d_in[5];
  const float* ca_w1  = (const float*)d_in[6];
  const float* ca_w2  = (const float*)d_in[7];
  float* out = (float*)d_out;

  float* kern4 = (float*)d_ws;                      // 32*64*4 = 8192 f
  float* att   = kern4 + B_ * C_ * 4;               // 2048 f
  unsigned short* wfrag = (unsigned short*)(att + B_ * C_);  // 4096 bf16

  da_prep<<<dim3(B_), dim3(64), 0, stream>>>(x1, W1, W2, ca_w1, ca_w2, conv_w,
                                             kern4, att, wfrag);
  da_main<<<dim3(NBLK), dim3(256), 0, stream>>>(x0, conv_b, kern4, att, wfrag,
                                                out);
}

// Round 12
// 63.099 us; speedup vs baseline: 2.8782x; 2.8782x over previous
//
#include <hip/hip_runtime.h>
#include <math.h>

#define B_ 32
#define C_ 64
#define L_ 16384
#define LT 32                           // l-columns per tile
#define NT 16                           // tiles per block (window = 512 l)
#define NBUF 3                          // staging buffers (depth-2 prefetch)
#define NBLK (B_ * (L_ / (LT * NT)))    // 1024 blocks -> exactly 4/CU resident

typedef __attribute__((ext_vector_type(8))) short short8;
typedef __attribute__((ext_vector_type(4))) float f32x4;

__device__ __forceinline__ unsigned short f2bf(float x) {
  unsigned int u = __builtin_bit_cast(unsigned int, x);
  u += 0x7fffu + ((u >> 16) & 1u);   // RNE
  return (unsigned short)(u >> 16);
}

__device__ __forceinline__ float lrelu(float x) {
  return x >= 0.f ? x : 0.1f * x;
}

__device__ __forceinline__ void load_lds_16(const void* g, void* l) {
  __builtin_amdgcn_global_load_lds(
      (const __attribute__((address_space(1))) void*)g,
      (__attribute__((address_space(3))) void*)l, 16, 0, 0);
}

// ---------------------------------------------------------------------------
// Prep (tiny): kern4[b,c,4], att[b,c], wfrag = conv_w as bf16 A-frags in
// per-lane load order (unchanged from r4-r11).
// ---------------------------------------------------------------------------
__global__ void da_prep(const float* __restrict__ x1,
                        const float* __restrict__ W1,
                        const float* __restrict__ W2,
                        const float* __restrict__ ca_w1,
                        const float* __restrict__ ca_w2,
                        const float* __restrict__ conv_w,
                        float* __restrict__ kern4,
                        float* __restrict__ att,
                        unsigned short* __restrict__ wfrag) {
  int b = blockIdx.x;      // 32
  int t = threadIdx.x;     // 64
  __shared__ float x1s[64], h[64], a1[8];
  x1s[t] = x1[b * 64 + t];
  __syncthreads();
  {
    const float* w1r = W1 + t * 64;
    float s = 0.f;
    #pragma unroll
    for (int i = 0; i < 64; ++i) s = fmaf(x1s[i], w1r[i], s);
    h[t] = lrelu(s);
  }
  if (t < 8) {
    const float* cw = ca_w1 + t * 64;
    float a = 0.f;
    #pragma unroll
    for (int i = 0; i < 64; ++i) a = fmaf(x1s[i], cw[i], a);
    a1[t] = lrelu(a);
  }
  __syncthreads();
  #pragma unroll
  for (int kk = 0; kk < 3; ++kk) {
    const float* w2r = W2 + (t * 3 + kk) * 64;
    float s2 = 0.f;
    #pragma unroll
    for (int i = 0; i < 64; ++i) s2 = fmaf(h[i], w2r[i], s2);
    kern4[(b * 64 + t) * 4 + kk] = s2;
  }
  kern4[(b * 64 + t) * 4 + 3] = 0.f;
  {
    float a = 0.f;
    #pragma unroll
    for (int r = 0; r < 8; ++r) a = fmaf(a1[r], ca_w2[t * 8 + r], a);
    att[b * 64 + t] = 1.f / (1.f + expf(-a));
  }
  if (b == 0) {
    #pragma unroll
    for (int kt = 0; kt < 2; ++kt)
      #pragma unroll
      for (int mt = 0; mt < 4; ++mt)
        #pragma unroll
        for (int j = 0; j < 8; ++j) {
          float e = conv_w[(mt * 16 + (t & 15)) * 64 + kt * 32 + (t >> 4) * 8 + j];
          wfrag[(((kt * 4 + mt) * 64) + t) * 8 + j] = f2bf(e);
        }
  }
}

// ---------------------------------------------------------------------------
// Main: r8 champion structure + FULL-LINE SINGLE-WAVE STORES.
// LT=32, NT=16, NBUF=3 depth-2, 1024 blocks, 36.75 KB LDS -> 4 blocks/CU,
// all resident. Per-wave in-loop vmem = 2 stage glds + 2 store dwordx4.
// Waits: t=0: vmcnt(2); 1<=t<NT-2: vmcnt(4); t=NT-2: vmcnt(2); t=NT-1: none.
// (queue <= s(t+1)[2] + st(t-1)[2] + s(t+2)[2]; vmcnt(4) retires s(t+1),
// which covers tile t AND t+1 -> right halo resident. Never 0 mid-loop.)
//
// Phase B reassignment: wave w owns o-quarter [16w,16w+16) x all 32 l:
//   af[kt] (mt=w), bf[kt][lh] from midT rows l=lh*16+m_lane (cross-wave ->
//   bar_mid kept), 4 MFMAs, acc[lh][r] -> (o=16w+qq*4+r, l=lh*16+m_lane).
// Epilogue: acc+bias+x0*att -> wave-private slab (XOR swizzle
//   word = o'*32 + (l ^ ((o'&7)<<2)); writes 2-way=free, b128 reads
//   conflict-free) -> 2 x global_store_dwordx4 per thread = 16 FULL 128B
//   lines per wave per iter, both halves from the same wave back-to-back.
// ---------------------------------------------------------------------------
__global__ __launch_bounds__(256, 4) void da_main(
    const float* __restrict__ x0,
    const float* __restrict__ conv_b,
    const float* __restrict__ kern4,
    const float* __restrict__ att,
    const unsigned short* __restrict__ wfrag,
    float* __restrict__ out) {
  __shared__ float x0s[NBUF][64 * LT];       // 3 x 8 KB
  __shared__ unsigned short midT[LT * 64];   // 4 KB
  __shared__ float slab[4 * 16 * 32];        // 8 KB, wave-private quarters
  __shared__ float haloL[2][64];

  int bid = blockIdx.x;            // 0..1023
  int b = bid >> 5;                // 32 windows per batch
  int base_l = (bid & 31) * (NT * LT);       // window = 512 l
  int tid = threadIdx.x;
  int lane = tid & 63;
  int wave = tid >> 6;

  int m_lane = lane & 15;
  int qq = lane >> 4;
  int kbase = qq * 8;

  const float* xb = x0 + (size_t)(b * 64) * L_;

  // ---- async stage of tile t1 into buffer dd (2 glds/wave, 8 rows each)
  auto STAGE = [&](int t1, int dd) {
    #pragma unroll
    for (int i = 0; i < 2; ++i) {
      int rg = (wave * 2 + i) * 8;           // row-group base
      int c = rg + (lane >> 3);
      int g = (lane & 7) ^ (c & 7);          // global chunk for LDS slot lane&7
      const float* gp = xb + (size_t)c * L_ + base_l + t1 * LT + g * 4;
      load_lds_16(gp, &x0s[dd][rg * LT]);
    }
  };

  // ---- pre-loop register loads (drained before first glds)
  short8 af[2];                    // A-frags: this wave's o-quarter (mt=wave)
  #pragma unroll
  for (int kt = 0; kt < 2; ++kt)
    af[kt] = *(const short8*)&wfrag[(((kt * 4 + wave) * 64) + lane) * 8];

  float4 kv = *(const float4*)&kern4[(b * 64 + lane) * 4];
  float k0 = kv.x, k1 = kv.y, k2 = kv.z;

  float cb_r[4], at_r[4];
  #pragma unroll
  for (int r = 0; r < 4; ++r) {
    int o = wave * 16 + qq * 4 + r;
    cb_r[r] = conv_b[o];
    at_r[r] = att[b * 64 + o];
  }

  // window-edge halos
  float hl0 = 0.f, hnL = 0.f;
  if (wave == 0 && base_l > 0) hl0 = xb[(size_t)lane * L_ + base_l - 1];
  if (wave == 3 && base_l + NT * LT < L_)
    hnL = xb[(size_t)lane * L_ + base_l + NT * LT];
  if (wave == 0) haloL[0][lane] = hl0;

  __syncthreads();                 // drains vmcnt(0)+lgkmcnt(0) of all above

  // ---- prologue: stage tiles 0 and 1
  STAGE(0, 0);
  STAGE(1, 1);

  // store-transpose constants
  int o2 = lane >> 2;              // 0..15: o within quarter (store phase)
  int lc = lane & 3;               // l-chunk (store phase)
  int slw = wave * 512;            // this wave's slab quarter (words)

  int cur = 0, nx1 = 1, nx2 = 2;   // rotating buffer indices
  for (int t = 0; t < NT; ++t) {
    // issue tile t+2 (deepest overlap; buf nx2 free since bar_mid(t-1))
    if (t + 2 < NT) STAGE(t + 2, nx2);

    // counted wait: tiles t AND t+1 staged; stores stay in flight
    if (t == 0)
      asm volatile("s_waitcnt vmcnt(2)" ::: "memory");
    else if (t < NT - 2)
      asm volatile("s_waitcnt vmcnt(4)" ::: "memory");
    else if (t == NT - 2)
      asm volatile("s_waitcnt vmcnt(2)" ::: "memory");
    // t == NT-1: tile NT-1 retired at t == NT-2; halo is hnL reg
    __builtin_amdgcn_s_barrier();            // bar1: tiles t, t+1 visible

    // ---- Phase A: depthwise 3-tap + lrelu -> midT rows [wave*8, wave*8+8)
    {
      int c = lane;
      int cs = c & 7;
      const float* row = &x0s[cur][c * LT];

      float4 q0 = *(const float4*)&row[((wave * 2 + 0) ^ cs) << 2];
      float4 q1 = *(const float4*)&row[((wave * 2 + 1) ^ cs) << 2];

      float prev, nxtv;
      if (wave == 0) {
        prev = (t == 0) ? hl0 : haloL[t & 1][c];
      } else {
        prev = row[(((wave * 2 - 1) ^ cs) << 2) + 3];   // word w0-1
      }
      if (wave == 3) {
        nxtv = (t == NT - 1) ? hnL : x0s[nx1][c * LT + (cs << 2)];
      } else {
        nxtv = row[((wave * 2 + 2) ^ cs) << 2];          // word w0+8
      }
      if (wave == 3 && t + 1 < NT) haloL[(t + 1) & 1][c] = q1.w;

      float m0 = fmaf(k0, prev, fmaf(k1, q0.x, k2 * q0.y));
      float m1 = fmaf(k0, q0.x, fmaf(k1, q0.y, k2 * q0.z));
      float m2 = fmaf(k0, q0.y, fmaf(k1, q0.z, k2 * q0.w));
      float m3 = fmaf(k0, q0.z, fmaf(k1, q0.w, k2 * q1.x));
      float m4 = fmaf(k0, q0.w, fmaf(k1, q1.x, k2 * q1.y));
      float m5 = fmaf(k0, q1.x, fmaf(k1, q1.y, k2 * q1.z));
      float m6 = fmaf(k0, q1.y, fmaf(k1, q1.z, k2 * q1.w));
      float m7 = fmaf(k0, q1.z, fmaf(k1, q1.w, k2 * nxtv));

      int lb = wave * 8;                      // lb ≡ 0 mod 8 -> swz = j<<3
      midT[(lb + 0) * 64 + (c ^ (0 << 3))] = f2bf(lrelu(m0));
      midT[(lb + 1) * 64 + (c ^ (1 << 3))] = f2bf(lrelu(m1));
      midT[(lb + 2) * 64 + (c ^ (2 << 3))] = f2bf(lrelu(m2));
      midT[(lb + 3) * 64 + (c ^ (3 << 3))] = f2bf(lrelu(m3));
      midT[(lb + 4) * 64 + (c ^ (4 << 3))] = f2bf(lrelu(m4));
      midT[(lb + 5) * 64 + (c ^ (5 << 3))] = f2bf(lrelu(m5));
      midT[(lb + 6) * 64 + (c ^ (6 << 3))] = f2bf(lrelu(m6));
      midT[(lb + 7) * 64 + (c ^ (7 << 3))] = f2bf(lrelu(m7));
    }

    // ---- xv pre-read (residual x0, this wave's o-quarter) before bar_mid
    float xv[2][4];
    #pragma unroll
    for (int lh = 0; lh < 2; ++lh)
      #pragma unroll
      for (int r = 0; r < 4; ++r) {
        int o = wave * 16 + qq * 4 + r;
        int l = lh * 16 + m_lane;
        xv[lh][r] =
            x0s[cur][o * LT + (((l >> 2) ^ (o & 7)) << 2) + (l & 3)];
      }

    asm volatile("s_waitcnt lgkmcnt(0)" ::: "memory");
    __builtin_amdgcn_s_barrier();            // bar_mid: midT ready, bufs free

    // ---- Phase B: o-quarter x 32 l via 4 MFMAs
    f32x4 acc[2];
    acc[0] = (f32x4){0.f, 0.f, 0.f, 0.f};
    acc[1] = (f32x4){0.f, 0.f, 0.f, 0.f};
    #pragma unroll
    for (int kt = 0; kt < 2; ++kt) {
      int cb = kt * 32 + kbase;
      #pragma unroll
      for (int lh = 0; lh < 2; ++lh) {
        int l = lh * 16 + m_lane;
        const short8 bf =
            *(const short8*)&midT[l * 64 + (cb ^ ((l & 7) << 3))];
        acc[lh] = __builtin_amdgcn_mfma_f32_16x16x32_bf16(af[kt], bf, acc[lh],
                                                          0, 0, 0);
      }
    }

    // ---- epilogue -> wave-private slab (swizzled), then 2 full-line stores
    #pragma unroll
    for (int lh = 0; lh < 2; ++lh)
      #pragma unroll
      for (int r = 0; r < 4; ++r) {
        int op = qq * 4 + r;                 // o within quarter
        int l = lh * 16 + m_lane;
        slab[slw + op * 32 + (l ^ ((op & 7) << 2))] =
            acc[lh][r] + cb_r[r] + xv[lh][r] * at_r[r];
      }

    {
      size_t orow = (size_t)(b * 64 + wave * 16 + o2) * L_ + base_l + t * LT;
      #pragma unroll
      for (int h = 0; h < 2; ++h) {
        int l = h * 16 + lc * 4;
        float4 v =
            *(const float4*)&slab[slw + o2 * 32 + (l ^ ((o2 & 7) << 2))];
        *(float4*)&out[orow + l] = v;
      }
    }

    int tmp = cur; cur = nx1; nx1 = nx2; nx2 = tmp;   // rotate buffers
  }
}

extern "C" void kernel_launch(void* const* d_in, const int* in_sizes, int n_in,
                              void* d_out, int out_size, void* d_ws, size_t ws_size,
                              hipStream_t stream) {
  const float* x0     = (const float*)d_in[0];
  const float* x1     = (const float*)d_in[1];
  const float* W1     = (const float*)d_in[2];
  const float* W2     = (const float*)d_in[3];
  const float* conv_w = (const float*)d_in[4];
  const float* conv_b = (const float*)d_in[5];
  const float* ca_w1  = (const float*)d_in[6];
  const float* ca_w2  = (const float*)d_in[7];
  float* out = (float*)d_out;

  float* kern4 = (float*)d_ws;                      // 32*64*4 = 8192 f
  float* att   = kern4 + B_ * C_ * 4;               // 2048 f
  unsigned short* wfrag = (unsigned short*)(att + B_ * C_);  // 4096 bf16

  da_prep<<<dim3(B_), dim3(64), 0, stream>>>(x1, W1, W2, ca_w1, ca_w2, conv_w,
                                             kern4, att, wfrag);
  da_main<<<dim3(NBLK), dim3(256), 0, stream>>>(x0, conv_b, kern4, att, wfrag,
                                                out);
}